// Round 11
// baseline (284.412 us; speedup 1.0000x reference)
//
#include <hip/hip_runtime.h>
#include <math.h>

// ---------------------------------------------------------------------------
// Problem constants
// ---------------------------------------------------------------------------
#define NB   128      // batch
#define HH   128
#define WW   128
#define HW   (HH*WW)          // 16384
#define POOLD 64              // pooled spatial
#define FC1_IN  8192          // 2*64*64
#define FC1_OUT 2048
#define FC2_OUT 1024

#define KS1  16               // fc1 split-K factor (grid 32x16=512 = 2/CU)
#define KS2  32               // fc2 split-K factor (grid 16x32=512 = 2/CU)

// workspace layout (in floats)
// h1 region [0, 4194304) is reused after fused_dcn:
//   part1: KS1 x (128*2048) = 4194304 floats at offset 0 (exact fit)
//   part2: KS2 x (128*1024) = 4194304 floats at offset 0 (part1 dead by then)
#define H1_OFF    0                       // 128*2*128*128 = 4194304
#define POOL_OFF  4194304                 // 128*8192      = 1048576
#define FC1_OFF   5242880                 // 128*2048      = 262144

typedef float f32x2 __attribute__((ext_vector_type(2)));

// ---------------------------------------------------------------------------
// Kernel 1: conv1  z=(x||mask) 9ch -> 2ch, 3x3, pad 1  ->  h1 (N,2,128,128)
// ---------------------------------------------------------------------------
__global__ __launch_bounds__(256) void conv1_kernel(
    const float* __restrict__ xin, const float* __restrict__ mask,
    const float* __restrict__ w1, const float* __restrict__ b1,
    float* __restrict__ h1)
{
    __shared__ float sw[164];              // 162 weights + 2 bias
    __shared__ float sh[9][10][132];       // ch x in-row x (col+1 pad each side)

    int tid = threadIdx.x;
    int n   = blockIdx.y;
    int r0  = blockIdx.x * 8;              // first output row of this block

    if (tid < 162) sw[tid] = w1[tid];
    if (tid < 2)   sw[162 + tid] = b1[tid];

    // zero the edge columns (global col -1 and 128)
    for (int i = tid; i < 90; i += 256) {
        int c  = i / 10;
        int ry = i - c * 10;
        sh[c][ry][0]   = 0.f;
        sh[c][ry][129] = 0.f;
    }

    // stage 9 x 10 x 128 floats as float4 rows (12 indep loads/thread)
    for (int idx = tid; idx < 2880; idx += 256) {
        int c   = idx / 320;
        int rem = idx - c * 320;
        int ry  = rem >> 5;
        int x4  = (rem & 31) << 2;
        int g   = r0 - 1 + ry;             // global input row
        float4 v = make_float4(0.f, 0.f, 0.f, 0.f);
        if (g >= 0 && g < HH) {
            const float* src = (c < 8) ? (xin + ((size_t)n * 8 + c) * HW)
                                       : (mask + (size_t)n * HW);
            v = *(const float4*)(src + (size_t)g * WW + x4);
        }
        float* d = &sh[c][ry][x4 + 1];
        d[0] = v.x; d[1] = v.y; d[2] = v.z; d[3] = v.w;
    }
    __syncthreads();

    int x  = tid & 127;                    // output col
    int yb = (tid >> 7) * 4;               // 0 or 4: first of 4 output rows

    float acc[4][2];
    #pragma unroll
    for (int r = 0; r < 4; ++r) { acc[r][0] = sw[162]; acc[r][1] = sw[163]; }

    for (int c = 0; c < 9; ++c) {
        float v[6][3];
        #pragma unroll
        for (int iy = 0; iy < 6; ++iy)
            #pragma unroll
            for (int kx = 0; kx < 3; ++kx)
                v[iy][kx] = sh[c][yb + iy][x + kx];
        #pragma unroll
        for (int r = 0; r < 4; ++r)
            #pragma unroll
            for (int ky = 0; ky < 3; ++ky)
                #pragma unroll
                for (int kx = 0; kx < 3; ++kx) {
                    float t = v[r + ky][kx];
                    acc[r][0] += t * sw[c * 9 + ky * 3 + kx];
                    acc[r][1] += t * sw[81 + c * 9 + ky * 3 + kx];
                }
    }

    #pragma unroll
    for (int r = 0; r < 4; ++r) {
        size_t base = (size_t)n * (2 * HW) + (size_t)(r0 + yb + r) * WW + x;
        h1[base]      = acc[r][0];
        h1[base + HW] = acc[r][1];
    }
}

// ---------------------------------------------------------------------------
// Kernel 2: fused  conv_off -> modulated deform conv -> 1x1+relu -> maxpool
//
//  Round-11 (on round-10's pk-fma offset conv):
//   - bilinear fallback is now WAVE-UNIFORMLY SKIPPED: the LDS fast path
//     always executes with a clamped (in-bounds) index; a `!__all(fast)`
//     scalar branch overwrites slow lanes from global. If-converted
//     fallback code (~630 issues/thread, never taken) no longer issues.
//   - bilinear interp packed across channels: {A,B} corner pairs are
//     adjacent in LDS -> f32x2 loads, 4 pk_fma + 1 pk_mul per pixel.
//  Bit-exact: fast lanes keep LDS values, slow lanes get fetchg results.
// ---------------------------------------------------------------------------
#define HALO_Y 5
#define HALO_X 6
#define SROWS  14          // 4 + 2*HALO_Y
#define SCOLS  140         // 128 + 2*HALO_X
#define PMAX   (SROWS * SCOLS - SCOLS - 2)   // max valid corner pair-index

__device__ __forceinline__ void fetchg(
    const float* __restrict__ h0, const float* __restrict__ hb,
    int yi, int xi, float& a, float& b)
{
    a = 0.f; b = 0.f;
    if ((unsigned)yi < (unsigned)HH && (unsigned)xi < (unsigned)WW) {
        a = h0[yi * WW + xi];
        b = hb[yi * WW + xi];
    }
}

__global__ __launch_bounds__(256, 4) void fused_dcn_kernel(
    const float* __restrict__ h1,
    const float* __restrict__ w_off,   // (27,2,3,3) = 27 rows of 18
    const float* __restrict__ w_dcn,   // (2,2,3,3)  = 36
    const float* __restrict__ b_dcn,   // (2)
    const float* __restrict__ w2,      // (2,2,1,1)  = 4
    const float* __restrict__ b2,      // (2)
    float* __restrict__ pooled)        // (N, 8192) = (N,2,64,64)
{
    __shared__ __align__(16) float sh[SROWS * SCOLS * 2];  // interleaved (y,x,c)

    int tid = threadIdx.x;
    int n   = blockIdx.y;
    int r0  = blockIdx.x * 4;              // full-res row base of this block

    // zero-fill the whole padded window (3920 floats = 980 float4)
    for (int i = tid; i < (SROWS * SCOLS * 2) / 4; i += 256)
        ((float4*)sh)[i] = make_float4(0.f, 0.f, 0.f, 0.f);
    __syncthreads();

    const float* h0g = h1 + (size_t)n * (2 * HW);
    const float* hbg = h0g + HW;

    // stage interior rows: float4 per channel, interleave into LDS
    for (int idx = tid; idx < SROWS * 32; idx += 256) {
        int ry = idx >> 5;
        int x4 = (idx & 31) << 2;
        int g  = r0 - HALO_Y + ry;
        if (g >= 0 && g < HH) {
            const float4 a = *(const float4*)(h0g + (size_t)g * WW + x4);
            const float4 b = *(const float4*)(hbg + (size_t)g * WW + x4);
            float* d = sh + (ry * SCOLS + HALO_X + x4) * 2;
            ((float4*)d)[0] = make_float4(a.x, b.x, a.y, b.y);
            ((float4*)d)[1] = make_float4(a.z, b.z, a.w, b.w);
        }
    }
    __syncthreads();

    int l  = tid & 63;
    int w  = tid >> 6;                      // wave 0..3
    int xh = w & 1;                         // x half
    int rp = w >> 1;                        // row pair 0/1
    int x  = l + 64 * xh;                   // owned column
    int yl0 = 2 * rp;                       // local output row (0 or 2)
    int yg0 = r0 + yl0;                     // global output row of pixel 0

    // taps for the 2 vertically adjacent pixels, packed {px0, px1}
    int tb0 = ((yl0 + HALO_Y) * SCOLS + (x + HALO_X)) * 2;   // int index
    int tb1 = tb0 + SCOLS * 2;

    f32x2 ha[9], hb[9];
    #pragma unroll
    for (int t = 0; t < 9; ++t) {
        int off = ((t / 3 - 1) * 3 * SCOLS + (t % 3 - 1) * 3) * 2;
        ha[t] = (f32x2){sh[tb0 + off],     sh[tb1 + off]};
        hb[t] = (f32x2){sh[tb0 + off + 1], sh[tb1 + off + 1]};
    }

    f32x2 accA = (f32x2){0.f, 0.f};   // out ch0 for {px0, px1}
    f32x2 accB = (f32x2){0.f, 0.f};   // out ch1 for {px0, px1}

    int lbase = (HALO_Y - r0) * SCOLS + HALO_X;   // add (y0*SCOLS + x0) -> pair idx

    #pragma unroll 1
    for (int k = 0; k < 9; ++k) {
        // wave-uniform weight rows, read straight from global -> s_load/SGPR
        const float* wyp = w_off + (2 * k) * 18;
        const float* wxp = w_off + (2 * k + 1) * 18;
        const float* wmp = w_off + (18 + k) * 18;

        f32x2 dy = (f32x2){0.f, 0.f};
        f32x2 dx = (f32x2){0.f, 0.f};
        f32x2 mv = (f32x2){0.f, 0.f};
        #pragma unroll
        for (int t = 0; t < 9; ++t) {
            float wyA = wyp[t], wyB = wyp[9 + t];
            float wxA = wxp[t], wxB = wxp[9 + t];
            float wmA = wmp[t], wmB = wmp[9 + t];
            dy += ha[t] * wyA + hb[t] * wyB;    // v_pk_fma_f32
            dx += ha[t] * wxA + hb[t] * wxB;
            mv += ha[t] * wmA + hb[t] * wmB;
        }

        int bty = (k / 3 - 1) * 3, btx = (k % 3 - 1) * 3;
        float wd0 = w_dcn[k],      wd1 = w_dcn[9 + k];
        float wd2 = w_dcn[18 + k], wd3 = w_dcn[27 + k];

        f32x2 sAB0, sAB1;   // {sA, sB} per pixel

        // ----- pixel 0 -----
        {
            float dy0 = dy.x, dx0 = dx.x;
            float mod = __builtin_amdgcn_rcpf(1.f + __expf(-mv.x));
            float py  = (float)(yg0 + bty) + dy0;
            float px_ = (float)(x + btx) + dx0;
            float y0f = floorf(py), x0f = floorf(px_);
            int   y0 = (int)y0f,   x0i = (int)x0f;
            float ly = py - y0f,   lx = px_ - x0f;

            // always-on LDS fast path with clamped index
            int p = lbase + y0 * SCOLS + x0i;
            int pcl = p < 0 ? 0 : (p > PMAX ? PMAX : p);
            int pi  = pcl * 2;
            f32x2 c00 = *(const f32x2*)&sh[pi];
            f32x2 c01 = *(const f32x2*)&sh[pi + 2];
            f32x2 c10 = *(const f32x2*)&sh[pi + SCOLS * 2];
            f32x2 c11 = *(const f32x2*)&sh[pi + SCOLS * 2 + 2];

            bool fast = fabsf(dy0) < 2.f && fabsf(dx0) < 3.f;
            if (!__all(fast)) {            // wave-uniform, statistically never
                if (!fast) {
                    float A00, B00, A01, B01, A10, B10, A11, B11;
                    fetchg(h0g, hbg, y0,     x0i,     A00, B00);
                    fetchg(h0g, hbg, y0,     x0i + 1, A01, B01);
                    fetchg(h0g, hbg, y0 + 1, x0i,     A10, B10);
                    fetchg(h0g, hbg, y0 + 1, x0i + 1, A11, B11);
                    c00 = (f32x2){A00, B00}; c01 = (f32x2){A01, B01};
                    c10 = (f32x2){A10, B10}; c11 = (f32x2){A11, B11};
                }
            }

            float omly = 1.f - ly, omlx = 1.f - lx;
            f32x2 s = c00 * (omly * omlx);
            s += c01 * (omly * lx);
            s += c10 * (ly * omlx);
            s += c11 * (ly * lx);
            sAB0 = s * mod;
        }

        // ----- pixel 1 (row yg0+1) -----
        {
            float dy1 = dy.y, dx1 = dx.y;
            float mod = __builtin_amdgcn_rcpf(1.f + __expf(-mv.y));
            float py  = (float)(yg0 + 1 + bty) + dy1;
            float px_ = (float)(x + btx) + dx1;
            float y0f = floorf(py), x0f = floorf(px_);
            int   y0 = (int)y0f,   x0i = (int)x0f;
            float ly = py - y0f,   lx = px_ - x0f;

            int p = lbase + y0 * SCOLS + x0i;
            int pcl = p < 0 ? 0 : (p > PMAX ? PMAX : p);
            int pi  = pcl * 2;
            f32x2 c00 = *(const f32x2*)&sh[pi];
            f32x2 c01 = *(const f32x2*)&sh[pi + 2];
            f32x2 c10 = *(const f32x2*)&sh[pi + SCOLS * 2];
            f32x2 c11 = *(const f32x2*)&sh[pi + SCOLS * 2 + 2];

            bool fast = fabsf(dy1) < 2.f && fabsf(dx1) < 3.f;
            if (!__all(fast)) {            // wave-uniform, statistically never
                if (!fast) {
                    float A00, B00, A01, B01, A10, B10, A11, B11;
                    fetchg(h0g, hbg, y0,     x0i,     A00, B00);
                    fetchg(h0g, hbg, y0,     x0i + 1, A01, B01);
                    fetchg(h0g, hbg, y0 + 1, x0i,     A10, B10);
                    fetchg(h0g, hbg, y0 + 1, x0i + 1, A11, B11);
                    c00 = (f32x2){A00, B00}; c01 = (f32x2){A01, B01};
                    c10 = (f32x2){A10, B10}; c11 = (f32x2){A11, B11};
                }
            }

            float omly = 1.f - ly, omlx = 1.f - lx;
            f32x2 s = c00 * (omly * omlx);
            s += c01 * (omly * lx);
            s += c10 * (ly * omlx);
            s += c11 * (ly * lx);
            sAB1 = s * mod;
        }

        // repack {sA, sB} per-pixel -> {px0, px1} per-channel, accumulate
        f32x2 sA = (f32x2){sAB0.x, sAB1.x};
        f32x2 sB = (f32x2){sAB0.y, sAB1.y};
        accA += sA * wd0 + sB * wd1;
        accB += sA * wd2 + sB * wd3;
    }

    // 1x1 conv + relu per pixel, vertical max in-thread (uniform scalars)
    float bd0 = b_dcn[0], bd1 = b_dcn[1];
    float W20 = w2[0], W21 = w2[1], W22 = w2[2], W23 = w2[3];
    float B20 = b2[0], B21 = b2[1];

    float v00 = accA.x + bd0, v01 = accB.x + bd1;
    float u00 = fmaxf(W20 * v00 + W21 * v01 + B20, 0.f);
    float u01 = fmaxf(W22 * v00 + W23 * v01 + B21, 0.f);
    float v10 = accA.y + bd0, v11 = accB.y + bd1;
    float u10 = fmaxf(W20 * v10 + W21 * v11 + B20, 0.f);
    float u11 = fmaxf(W22 * v10 + W23 * v11 + B21, 0.f);
    float m0 = fmaxf(u00, u10);
    float m1 = fmaxf(u01, u11);

    // horizontal max with lane partner (x ^ 1)
    m0 = fmaxf(m0, __shfl_xor(m0, 1, 64));
    m1 = fmaxf(m1, __shfl_xor(m1, 1, 64));

    if ((l & 1) == 0) {
        int pr = blockIdx.x * 2 + rp;
        int pc = (l >> 1) + 32 * xh;
        size_t pb = (size_t)n * FC1_IN + (size_t)pr * POOLD + pc;
        pooled[pb]        = m0;
        pooled[pb + 4096] = m1;
    }
}

// ---------------------------------------------------------------------------
// Kernel 3: bf16-MFMA GEMM  Cpart[ks] = A(128 x kchunk) @ B(Nc x kchunk)^T
//  (round-9 plain-store split-K structure; BK=64)
// ---------------------------------------------------------------------------
typedef __bf16 bf16x8 __attribute__((ext_vector_type(8)));
typedef float  f32x4  __attribute__((ext_vector_type(4)));

#define LDT2 72      // row stride in bf16 for BK=64 tiles (16B aligned, 2-way worst)

__device__ __forceinline__ unsigned short f2bf(float f) {
    unsigned int u = __float_as_uint(f);
    return (unsigned short)((u + 0x7fffu + ((u >> 16) & 1u)) >> 16);
}

__global__ __launch_bounds__(256, 4) void gemm_bf16_splitk(
    const float* __restrict__ A, const float* __restrict__ B,
    float* __restrict__ Cpart, int K, int Nc, int kchunk, int relu_a)
{
    __shared__ __align__(16) unsigned short As[128 * LDT2];  // 18.4 KB
    __shared__ __align__(16) unsigned short Bs[64 * LDT2];   //  9.2 KB

    int tid = threadIdx.x;
    int jt  = blockIdx.x;                  // N tile (64 cols)
    int k0  = blockIdx.y * kchunk;
    int iters = kchunk >> 6;               // BK = 64

    int t16 = tid >> 4;                    // 0..15
    int c64 = (tid & 15) << 2;             // 0,4,..,60
    int t4  = tid >> 2;                    // 0..63
    int cB  = (tid & 3) << 4;              // 0,16,32,48

    const float* Ag = A + (size_t)t16 * K + k0 + c64;
    const float* Bg = B + (size_t)(jt * 64 + t4) * K + k0 + cB;

    float4 pa[8]; float4 pb[4];
    #pragma unroll
    for (int p = 0; p < 8; ++p) pa[p] = *(const float4*)(Ag + (size_t)(p * 16) * K);
    #pragma unroll
    for (int q = 0; q < 4; ++q) pb[q] = *(const float4*)(Bg + q * 4);

    int lane = tid & 63;
    int w    = tid >> 6;                   // wave 0..3 -> rows w*32..w*32+31
    int quad = lane >> 4;
    int r    = lane & 15;

    f32x4 acc[2][4];
    #pragma unroll
    for (int mt = 0; mt < 2; ++mt)
        #pragma unroll
        for (int nt = 0; nt < 4; ++nt)
            acc[mt][nt] = (f32x4){0.f, 0.f, 0.f, 0.f};

    for (int it = 0; it < iters; ++it) {
        #pragma unroll
        for (int p = 0; p < 8; ++p) {
            float4 v = pa[p];
            if (relu_a) {
                v.x = fmaxf(v.x, 0.f); v.y = fmaxf(v.y, 0.f);
                v.z = fmaxf(v.z, 0.f); v.w = fmaxf(v.w, 0.f);
            }
            ushort4 s = make_ushort4(f2bf(v.x), f2bf(v.y), f2bf(v.z), f2bf(v.w));
            *(ushort4*)&As[(t16 + p * 16) * LDT2 + c64] = s;
        }
        #pragma unroll
        for (int q = 0; q < 4; ++q) {
            float4 v = pb[q];
            ushort4 s = make_ushort4(f2bf(v.x), f2bf(v.y), f2bf(v.z), f2bf(v.w));
            *(ushort4*)&Bs[t4 * LDT2 + cB + q * 4] = s;
        }
        __syncthreads();

        if (it + 1 < iters) {
            Ag += 64; Bg += 64;
            #pragma unroll
            for (int p = 0; p < 8; ++p) pa[p] = *(const float4*)(Ag + (size_t)(p * 16) * K);
            #pragma unroll
            for (int q = 0; q < 4; ++q) pb[q] = *(const float4*)(Bg + q * 4);
        }

        #pragma unroll
        for (int ks = 0; ks < 2; ++ks) {
            bf16x8 af[2];
            #pragma unroll
            for (int mt = 0; mt < 2; ++mt)
                af[mt] = *(const bf16x8*)&As[(w * 32 + mt * 16 + r) * LDT2
                                             + ks * 32 + quad * 8];
            bf16x8 bfr[4];
            #pragma unroll
            for (int nt = 0; nt < 4; ++nt)
                bfr[nt] = *(const bf16x8*)&Bs[(nt * 16 + r) * LDT2
                                              + ks * 32 + quad * 8];

            #pragma unroll
            for (int mt = 0; mt < 2; ++mt)
                #pragma unroll
                for (int nt = 0; nt < 4; ++nt)
                    acc[mt][nt] = __builtin_amdgcn_mfma_f32_16x16x32_bf16(
                        af[mt], bfr[nt], acc[mt][nt], 0, 0, 0);
        }

        __syncthreads();
    }

    // epilogue: plain stores into this split's private partial tile
    float* Cp = Cpart + (size_t)blockIdx.y * (128 * Nc);
    #pragma unroll
    for (int mt = 0; mt < 2; ++mt) {
        int mrow = w * 32 + mt * 16 + quad * 4;
        #pragma unroll
        for (int nt = 0; nt < 4; ++nt) {
            int col = jt * 64 + nt * 16 + r;
            #pragma unroll
            for (int i = 0; i < 4; ++i)
                Cp[(size_t)(mrow + i) * Nc + col] = acc[mt][nt][i];
        }
    }
}

// ---------------------------------------------------------------------------
// Kernel 4: reduce fc1 partials + bias -> fc1_out (pre-relu, as before)
// ---------------------------------------------------------------------------
__global__ __launch_bounds__(256) void reduce_fc1_kernel(
    const float* __restrict__ part, const float* __restrict__ bias,
    float* __restrict__ outp)
{
    int i = blockIdx.x * 256 + threadIdx.x;       // float4 index
    float4 s = ((const float4*)part)[i];
    #pragma unroll
    for (int p = 1; p < KS1; ++p) {
        float4 v = ((const float4*)part)[(size_t)p * (NB * FC1_OUT / 4) + i];
        s.x += v.x; s.y += v.y; s.z += v.z; s.w += v.w;
    }
    float4 b = ((const float4*)bias)[i & (FC1_OUT / 4 - 1)];
    s.x += b.x; s.y += b.y; s.z += b.z; s.w += b.w;
    ((float4*)outp)[i] = s;
}

// ---------------------------------------------------------------------------
// Kernel 5: io layer — sums fc2 partials, +bias, relu, dot io_w, sigmoid
// ---------------------------------------------------------------------------
__global__ __launch_bounds__(256) void io_kernel(
    const float* __restrict__ part2, const float* __restrict__ fc2_b,
    const float* __restrict__ io_w, const float* __restrict__ io_b,
    float* __restrict__ out)
{
    int n = blockIdx.x;
    int tid = threadIdx.x;
    size_t base = (size_t)n * FC2_OUT + tid * 4;

    float4 v = ((const float4*)fc2_b)[tid];       // start from bias
    #pragma unroll
    for (int p = 0; p < KS2; ++p) {
        float4 t = *(const float4*)(part2 + (size_t)p * (NB * FC2_OUT) + base);
        v.x += t.x; v.y += t.y; v.z += t.z; v.w += t.w;
    }
    float4 wv = *(const float4*)(io_w + tid * 4);
    float s = fmaxf(v.x, 0.f) * wv.x + fmaxf(v.y, 0.f) * wv.y
            + fmaxf(v.z, 0.f) * wv.z + fmaxf(v.w, 0.f) * wv.w;
    #pragma unroll
    for (int off = 32; off > 0; off >>= 1)
        s += __shfl_down(s, off, 64);
    __shared__ float red[4];
    if ((tid & 63) == 0) red[tid >> 6] = s;
    __syncthreads();
    if (tid == 0) {
        float t = red[0] + red[1] + red[2] + red[3] + io_b[0];
        out[n] = 1.f / (1.f + expf(-t));
    }
}

// ---------------------------------------------------------------------------
// launch
// ---------------------------------------------------------------------------
extern "C" void kernel_launch(void* const* d_in, const int* in_sizes, int n_in,
                              void* d_out, int out_size, void* d_ws, size_t ws_size,
                              hipStream_t stream)
{
    const float* mask  = (const float*)d_in[0];
    const float* x     = (const float*)d_in[1];
    const float* w1    = (const float*)d_in[2];
    const float* b1    = (const float*)d_in[3];
    const float* w_off = (const float*)d_in[4];
    const float* w_dcn = (const float*)d_in[5];
    const float* b_dcn = (const float*)d_in[6];
    const float* w2    = (const float*)d_in[7];
    const float* b2    = (const float*)d_in[8];
    const float* fc1_w = (const float*)d_in[9];
    const float* fc1_b = (const float*)d_in[10];
    const float* fc2_w = (const float*)d_in[11];
    const float* fc2_b = (const float*)d_in[12];
    const float* io_w  = (const float*)d_in[13];
    const float* io_b  = (const float*)d_in[14];

    float* ws      = (float*)d_ws;
    float* h1      = ws + H1_OFF;
    float* pooled  = ws + POOL_OFF;
    float* fc1_out = ws + FC1_OFF;
    float* part1   = ws + H1_OFF;          // reuse h1 region (dead after DCN)
    float* part2   = ws + H1_OFF;          // reuse again (part1 dead after reduce)
    float* out     = (float*)d_out;

    // conv1: (N,9,128,128) -> h1 (N,2,128,128)
    conv1_kernel<<<dim3(16, NB), 256, 0, stream>>>(x, mask, w1, b1, h1);

    // fused offset-conv + DCN + 1x1 relu + 2x2 maxpool -> pooled (N,8192)
    fused_dcn_kernel<<<dim3(32, NB), 256, 0, stream>>>(
        h1, w_off, w_dcn, b_dcn, w2, b2, pooled);

    // fc1: (128,8192)@(8192,2048) bf16 MFMA, split-K 16 -> 512 blocks (2/CU)
    gemm_bf16_splitk<<<dim3(FC1_OUT / 64, KS1), 256, 0, stream>>>(
        pooled, fc1_w, part1, FC1_IN, FC1_OUT, FC1_IN / KS1, 0);

    // reduce fc1 partials + bias -> fc1_out
    reduce_fc1_kernel<<<NB * FC1_OUT / 4 / 256, 256, 0, stream>>>(
        part1, fc1_b, fc1_out);

    // fc2: relu(fc1) (128,2048)@(2048,1024) bf16 MFMA, split-K 32 -> 512 blocks
    gemm_bf16_splitk<<<dim3(FC2_OUT / 64, KS2), 256, 0, stream>>>(
        fc1_out, fc2_w, part2, FC1_OUT, FC2_OUT, FC1_OUT / KS2, 1);

    // io: sum fc2 partials + bias, relu, dot io_w, sigmoid -> out (128)
    io_kernel<<<NB, 256, 0, stream>>>(part2, fc2_b, io_w, io_b, out);
}

// Round 12
// 281.668 us; speedup vs baseline: 1.0097x; 1.0097x over previous
//
#include <hip/hip_runtime.h>
#include <math.h>

// ---------------------------------------------------------------------------
// Problem constants
// ---------------------------------------------------------------------------
#define NB   128      // batch
#define HH   128
#define WW   128
#define HW   (HH*WW)          // 16384
#define POOLD 64              // pooled spatial
#define FC1_IN  8192          // 2*64*64
#define FC1_OUT 2048
#define FC2_OUT 1024

#define KS1  16               // fc1 split-K factor (grid 32x16=512 = 2/CU)
#define KS2  32               // fc2 split-K factor (grid 16x32=512 = 2/CU)

// workspace layout (in floats)
// h1 region [0, 4194304) is reused after fused_dcn:
//   part1: KS1 x (128*2048) = 4194304 floats at offset 0 (exact fit)
//   part2: KS2 x (128*1024) = 4194304 floats at offset 0 (part1 dead by then)
#define H1_OFF    0                       // 128*2*128*128 = 4194304
#define POOL_OFF  4194304                 // 128*8192      = 1048576
#define FC1_OFF   5242880                 // 128*2048      = 262144

typedef float f32x2 __attribute__((ext_vector_type(2)));

// ---------------------------------------------------------------------------
// Kernel 1: conv1  z=(x||mask) 9ch -> 2ch, 3x3, pad 1  ->  h1 (N,2,128,128)
// ---------------------------------------------------------------------------
__global__ __launch_bounds__(256) void conv1_kernel(
    const float* __restrict__ xin, const float* __restrict__ mask,
    const float* __restrict__ w1, const float* __restrict__ b1,
    float* __restrict__ h1)
{
    __shared__ float sw[164];              // 162 weights + 2 bias
    __shared__ float sh[9][10][132];       // ch x in-row x (col+1 pad each side)

    int tid = threadIdx.x;
    int n   = blockIdx.y;
    int r0  = blockIdx.x * 8;              // first output row of this block

    if (tid < 162) sw[tid] = w1[tid];
    if (tid < 2)   sw[162 + tid] = b1[tid];

    // zero the edge columns (global col -1 and 128)
    for (int i = tid; i < 90; i += 256) {
        int c  = i / 10;
        int ry = i - c * 10;
        sh[c][ry][0]   = 0.f;
        sh[c][ry][129] = 0.f;
    }

    // stage 9 x 10 x 128 floats as float4 rows (12 indep loads/thread)
    for (int idx = tid; idx < 2880; idx += 256) {
        int c   = idx / 320;
        int rem = idx - c * 320;
        int ry  = rem >> 5;
        int x4  = (rem & 31) << 2;
        int g   = r0 - 1 + ry;             // global input row
        float4 v = make_float4(0.f, 0.f, 0.f, 0.f);
        if (g >= 0 && g < HH) {
            const float* src = (c < 8) ? (xin + ((size_t)n * 8 + c) * HW)
                                       : (mask + (size_t)n * HW);
            v = *(const float4*)(src + (size_t)g * WW + x4);
        }
        float* d = &sh[c][ry][x4 + 1];
        d[0] = v.x; d[1] = v.y; d[2] = v.z; d[3] = v.w;
    }
    __syncthreads();

    int x  = tid & 127;                    // output col
    int yb = (tid >> 7) * 4;               // 0 or 4: first of 4 output rows

    float acc[4][2];
    #pragma unroll
    for (int r = 0; r < 4; ++r) { acc[r][0] = sw[162]; acc[r][1] = sw[163]; }

    for (int c = 0; c < 9; ++c) {
        float v[6][3];
        #pragma unroll
        for (int iy = 0; iy < 6; ++iy)
            #pragma unroll
            for (int kx = 0; kx < 3; ++kx)
                v[iy][kx] = sh[c][yb + iy][x + kx];
        #pragma unroll
        for (int r = 0; r < 4; ++r)
            #pragma unroll
            for (int ky = 0; ky < 3; ++ky)
                #pragma unroll
                for (int kx = 0; kx < 3; ++kx) {
                    float t = v[r + ky][kx];
                    acc[r][0] += t * sw[c * 9 + ky * 3 + kx];
                    acc[r][1] += t * sw[81 + c * 9 + ky * 3 + kx];
                }
    }

    #pragma unroll
    for (int r = 0; r < 4; ++r) {
        size_t base = (size_t)n * (2 * HW) + (size_t)(r0 + yb + r) * WW + x;
        h1[base]      = acc[r][0];
        h1[base + HW] = acc[r][1];
    }
}

// ---------------------------------------------------------------------------
// Kernel 2: fused  conv_off -> modulated deform conv -> 1x1+relu -> maxpool
//
//  Round-12: drop the `,4` min-waves hint from launch_bounds. It was
//  protection against the r3/r4 spills; at VGPR=40 it no longer protects
//  anything and the kernel sits at 52% occupancy (4 blocks/CU) despite
//  resources allowing 8 (VGPR 40, LDS 15.9KB). The kernel is partially
//  latency-bound (VALUBusy 72%, serial per-pixel chains) -> more resident
//  waves fill the 28% idle.
//  (r11 structure: pk-fma offset conv, channel-packed bilinear, clamped
//   always-LDS fast path + wave-uniform fallback, SGPR weights.)
// ---------------------------------------------------------------------------
#define HALO_Y 5
#define HALO_X 6
#define SROWS  14          // 4 + 2*HALO_Y
#define SCOLS  140         // 128 + 2*HALO_X
#define PMAX   (SROWS * SCOLS - SCOLS - 2)   // max valid corner pair-index

__device__ __forceinline__ void fetchg(
    const float* __restrict__ h0, const float* __restrict__ hb,
    int yi, int xi, float& a, float& b)
{
    a = 0.f; b = 0.f;
    if ((unsigned)yi < (unsigned)HH && (unsigned)xi < (unsigned)WW) {
        a = h0[yi * WW + xi];
        b = hb[yi * WW + xi];
    }
}

__global__ __launch_bounds__(256) void fused_dcn_kernel(
    const float* __restrict__ h1,
    const float* __restrict__ w_off,   // (27,2,3,3) = 27 rows of 18
    const float* __restrict__ w_dcn,   // (2,2,3,3)  = 36
    const float* __restrict__ b_dcn,   // (2)
    const float* __restrict__ w2,      // (2,2,1,1)  = 4
    const float* __restrict__ b2,      // (2)
    float* __restrict__ pooled)        // (N, 8192) = (N,2,64,64)
{
    __shared__ __align__(16) float sh[SROWS * SCOLS * 2];  // interleaved (y,x,c)

    int tid = threadIdx.x;
    int n   = blockIdx.y;
    int r0  = blockIdx.x * 4;              // full-res row base of this block

    // zero-fill the whole padded window (3920 floats = 980 float4)
    for (int i = tid; i < (SROWS * SCOLS * 2) / 4; i += 256)
        ((float4*)sh)[i] = make_float4(0.f, 0.f, 0.f, 0.f);
    __syncthreads();

    const float* h0g = h1 + (size_t)n * (2 * HW);
    const float* hbg = h0g + HW;

    // stage interior rows: float4 per channel, interleave into LDS
    for (int idx = tid; idx < SROWS * 32; idx += 256) {
        int ry = idx >> 5;
        int x4 = (idx & 31) << 2;
        int g  = r0 - HALO_Y + ry;
        if (g >= 0 && g < HH) {
            const float4 a = *(const float4*)(h0g + (size_t)g * WW + x4);
            const float4 b = *(const float4*)(hbg + (size_t)g * WW + x4);
            float* d = sh + (ry * SCOLS + HALO_X + x4) * 2;
            ((float4*)d)[0] = make_float4(a.x, b.x, a.y, b.y);
            ((float4*)d)[1] = make_float4(a.z, b.z, a.w, b.w);
        }
    }
    __syncthreads();

    int l  = tid & 63;
    int w  = tid >> 6;                      // wave 0..3
    int xh = w & 1;                         // x half
    int rp = w >> 1;                        // row pair 0/1
    int x  = l + 64 * xh;                   // owned column
    int yl0 = 2 * rp;                       // local output row (0 or 2)
    int yg0 = r0 + yl0;                     // global output row of pixel 0

    // taps for the 2 vertically adjacent pixels, packed {px0, px1}
    int tb0 = ((yl0 + HALO_Y) * SCOLS + (x + HALO_X)) * 2;   // int index
    int tb1 = tb0 + SCOLS * 2;

    f32x2 ha[9], hb[9];
    #pragma unroll
    for (int t = 0; t < 9; ++t) {
        int off = ((t / 3 - 1) * 3 * SCOLS + (t % 3 - 1) * 3) * 2;
        ha[t] = (f32x2){sh[tb0 + off],     sh[tb1 + off]};
        hb[t] = (f32x2){sh[tb0 + off + 1], sh[tb1 + off + 1]};
    }

    f32x2 accA = (f32x2){0.f, 0.f};   // out ch0 for {px0, px1}
    f32x2 accB = (f32x2){0.f, 0.f};   // out ch1 for {px0, px1}

    int lbase = (HALO_Y - r0) * SCOLS + HALO_X;   // add (y0*SCOLS + x0) -> pair idx

    #pragma unroll 1
    for (int k = 0; k < 9; ++k) {
        // wave-uniform weight rows, read straight from global -> s_load/SGPR
        const float* wyp = w_off + (2 * k) * 18;
        const float* wxp = w_off + (2 * k + 1) * 18;
        const float* wmp = w_off + (18 + k) * 18;

        f32x2 dy = (f32x2){0.f, 0.f};
        f32x2 dx = (f32x2){0.f, 0.f};
        f32x2 mv = (f32x2){0.f, 0.f};
        #pragma unroll
        for (int t = 0; t < 9; ++t) {
            float wyA = wyp[t], wyB = wyp[9 + t];
            float wxA = wxp[t], wxB = wxp[9 + t];
            float wmA = wmp[t], wmB = wmp[9 + t];
            dy += ha[t] * wyA + hb[t] * wyB;    // v_pk_fma_f32
            dx += ha[t] * wxA + hb[t] * wxB;
            mv += ha[t] * wmA + hb[t] * wmB;
        }

        int bty = (k / 3 - 1) * 3, btx = (k % 3 - 1) * 3;
        float wd0 = w_dcn[k],      wd1 = w_dcn[9 + k];
        float wd2 = w_dcn[18 + k], wd3 = w_dcn[27 + k];

        f32x2 sAB0, sAB1;   // {sA, sB} per pixel

        // ----- pixel 0 -----
        {
            float dy0 = dy.x, dx0 = dx.x;
            float mod = __builtin_amdgcn_rcpf(1.f + __expf(-mv.x));
            float py  = (float)(yg0 + bty) + dy0;
            float px_ = (float)(x + btx) + dx0;
            float y0f = floorf(py), x0f = floorf(px_);
            int   y0 = (int)y0f,   x0i = (int)x0f;
            float ly = py - y0f,   lx = px_ - x0f;

            // always-on LDS fast path with clamped index
            int p = lbase + y0 * SCOLS + x0i;
            int pcl = p < 0 ? 0 : (p > PMAX ? PMAX : p);
            int pi  = pcl * 2;
            f32x2 c00 = *(const f32x2*)&sh[pi];
            f32x2 c01 = *(const f32x2*)&sh[pi + 2];
            f32x2 c10 = *(const f32x2*)&sh[pi + SCOLS * 2];
            f32x2 c11 = *(const f32x2*)&sh[pi + SCOLS * 2 + 2];

            bool fast = fabsf(dy0) < 2.f && fabsf(dx0) < 3.f;
            if (!__all(fast)) {            // wave-uniform, statistically never
                if (!fast) {
                    float A00, B00, A01, B01, A10, B10, A11, B11;
                    fetchg(h0g, hbg, y0,     x0i,     A00, B00);
                    fetchg(h0g, hbg, y0,     x0i + 1, A01, B01);
                    fetchg(h0g, hbg, y0 + 1, x0i,     A10, B10);
                    fetchg(h0g, hbg, y0 + 1, x0i + 1, A11, B11);
                    c00 = (f32x2){A00, B00}; c01 = (f32x2){A01, B01};
                    c10 = (f32x2){A10, B10}; c11 = (f32x2){A11, B11};
                }
            }

            float omly = 1.f - ly, omlx = 1.f - lx;
            f32x2 s = c00 * (omly * omlx);
            s += c01 * (omly * lx);
            s += c10 * (ly * omlx);
            s += c11 * (ly * lx);
            sAB0 = s * mod;
        }

        // ----- pixel 1 (row yg0+1) -----
        {
            float dy1 = dy.y, dx1 = dx.y;
            float mod = __builtin_amdgcn_rcpf(1.f + __expf(-mv.y));
            float py  = (float)(yg0 + 1 + bty) + dy1;
            float px_ = (float)(x + btx) + dx1;
            float y0f = floorf(py), x0f = floorf(px_);
            int   y0 = (int)y0f,   x0i = (int)x0f;
            float ly = py - y0f,   lx = px_ - x0f;

            int p = lbase + y0 * SCOLS + x0i;
            int pcl = p < 0 ? 0 : (p > PMAX ? PMAX : p);
            int pi  = pcl * 2;
            f32x2 c00 = *(const f32x2*)&sh[pi];
            f32x2 c01 = *(const f32x2*)&sh[pi + 2];
            f32x2 c10 = *(const f32x2*)&sh[pi + SCOLS * 2];
            f32x2 c11 = *(const f32x2*)&sh[pi + SCOLS * 2 + 2];

            bool fast = fabsf(dy1) < 2.f && fabsf(dx1) < 3.f;
            if (!__all(fast)) {            // wave-uniform, statistically never
                if (!fast) {
                    float A00, B00, A01, B01, A10, B10, A11, B11;
                    fetchg(h0g, hbg, y0,     x0i,     A00, B00);
                    fetchg(h0g, hbg, y0,     x0i + 1, A01, B01);
                    fetchg(h0g, hbg, y0 + 1, x0i,     A10, B10);
                    fetchg(h0g, hbg, y0 + 1, x0i + 1, A11, B11);
                    c00 = (f32x2){A00, B00}; c01 = (f32x2){A01, B01};
                    c10 = (f32x2){A10, B10}; c11 = (f32x2){A11, B11};
                }
            }

            float omly = 1.f - ly, omlx = 1.f - lx;
            f32x2 s = c00 * (omly * omlx);
            s += c01 * (omly * lx);
            s += c10 * (ly * omlx);
            s += c11 * (ly * lx);
            sAB1 = s * mod;
        }

        // repack {sA, sB} per-pixel -> {px0, px1} per-channel, accumulate
        f32x2 sA = (f32x2){sAB0.x, sAB1.x};
        f32x2 sB = (f32x2){sAB0.y, sAB1.y};
        accA += sA * wd0 + sB * wd1;
        accB += sA * wd2 + sB * wd3;
    }

    // 1x1 conv + relu per pixel, vertical max in-thread (uniform scalars)
    float bd0 = b_dcn[0], bd1 = b_dcn[1];
    float W20 = w2[0], W21 = w2[1], W22 = w2[2], W23 = w2[3];
    float B20 = b2[0], B21 = b2[1];

    float v00 = accA.x + bd0, v01 = accB.x + bd1;
    float u00 = fmaxf(W20 * v00 + W21 * v01 + B20, 0.f);
    float u01 = fmaxf(W22 * v00 + W23 * v01 + B21, 0.f);
    float v10 = accA.y + bd0, v11 = accB.y + bd1;
    float u10 = fmaxf(W20 * v10 + W21 * v11 + B20, 0.f);
    float u11 = fmaxf(W22 * v10 + W23 * v11 + B21, 0.f);
    float m0 = fmaxf(u00, u10);
    float m1 = fmaxf(u01, u11);

    // horizontal max with lane partner (x ^ 1)
    m0 = fmaxf(m0, __shfl_xor(m0, 1, 64));
    m1 = fmaxf(m1, __shfl_xor(m1, 1, 64));

    if ((l & 1) == 0) {
        int pr = blockIdx.x * 2 + rp;
        int pc = (l >> 1) + 32 * xh;
        size_t pb = (size_t)n * FC1_IN + (size_t)pr * POOLD + pc;
        pooled[pb]        = m0;
        pooled[pb + 4096] = m1;
    }
}

// ---------------------------------------------------------------------------
// Kernel 3: bf16-MFMA GEMM  Cpart[ks] = A(128 x kchunk) @ B(Nc x kchunk)^T
//  (round-9 plain-store split-K structure; BK=64)
// ---------------------------------------------------------------------------
typedef __bf16 bf16x8 __attribute__((ext_vector_type(8)));
typedef float  f32x4  __attribute__((ext_vector_type(4)));

#define LDT2 72      // row stride in bf16 for BK=64 tiles (16B aligned, 2-way worst)

__device__ __forceinline__ unsigned short f2bf(float f) {
    unsigned int u = __float_as_uint(f);
    return (unsigned short)((u + 0x7fffu + ((u >> 16) & 1u)) >> 16);
}

__global__ __launch_bounds__(256, 4) void gemm_bf16_splitk(
    const float* __restrict__ A, const float* __restrict__ B,
    float* __restrict__ Cpart, int K, int Nc, int kchunk, int relu_a)
{
    __shared__ __align__(16) unsigned short As[128 * LDT2];  // 18.4 KB
    __shared__ __align__(16) unsigned short Bs[64 * LDT2];   //  9.2 KB

    int tid = threadIdx.x;
    int jt  = blockIdx.x;                  // N tile (64 cols)
    int k0  = blockIdx.y * kchunk;
    int iters = kchunk >> 6;               // BK = 64

    int t16 = tid >> 4;                    // 0..15
    int c64 = (tid & 15) << 2;             // 0,4,..,60
    int t4  = tid >> 2;                    // 0..63
    int cB  = (tid & 3) << 4;              // 0,16,32,48

    const float* Ag = A + (size_t)t16 * K + k0 + c64;
    const float* Bg = B + (size_t)(jt * 64 + t4) * K + k0 + cB;

    float4 pa[8]; float4 pb[4];
    #pragma unroll
    for (int p = 0; p < 8; ++p) pa[p] = *(const float4*)(Ag + (size_t)(p * 16) * K);
    #pragma unroll
    for (int q = 0; q < 4; ++q) pb[q] = *(const float4*)(Bg + q * 4);

    int lane = tid & 63;
    int w    = tid >> 6;                   // wave 0..3 -> rows w*32..w*32+31
    int quad = lane >> 4;
    int r    = lane & 15;

    f32x4 acc[2][4];
    #pragma unroll
    for (int mt = 0; mt < 2; ++mt)
        #pragma unroll
        for (int nt = 0; nt < 4; ++nt)
            acc[mt][nt] = (f32x4){0.f, 0.f, 0.f, 0.f};

    for (int it = 0; it < iters; ++it) {
        #pragma unroll
        for (int p = 0; p < 8; ++p) {
            float4 v = pa[p];
            if (relu_a) {
                v.x = fmaxf(v.x, 0.f); v.y = fmaxf(v.y, 0.f);
                v.z = fmaxf(v.z, 0.f); v.w = fmaxf(v.w, 0.f);
            }
            ushort4 s = make_ushort4(f2bf(v.x), f2bf(v.y), f2bf(v.z), f2bf(v.w));
            *(ushort4*)&As[(t16 + p * 16) * LDT2 + c64] = s;
        }
        #pragma unroll
        for (int q = 0; q < 4; ++q) {
            float4 v = pb[q];
            ushort4 s = make_ushort4(f2bf(v.x), f2bf(v.y), f2bf(v.z), f2bf(v.w));
            *(ushort4*)&Bs[t4 * LDT2 + cB + q * 4] = s;
        }
        __syncthreads();

        if (it + 1 < iters) {
            Ag += 64; Bg += 64;
            #pragma unroll
            for (int p = 0; p < 8; ++p) pa[p] = *(const float4*)(Ag + (size_t)(p * 16) * K);
            #pragma unroll
            for (int q = 0; q < 4; ++q) pb[q] = *(const float4*)(Bg + q * 4);
        }

        #pragma unroll
        for (int ks = 0; ks < 2; ++ks) {
            bf16x8 af[2];
            #pragma unroll
            for (int mt = 0; mt < 2; ++mt)
                af[mt] = *(const bf16x8*)&As[(w * 32 + mt * 16 + r) * LDT2
                                             + ks * 32 + quad * 8];
            bf16x8 bfr[4];
            #pragma unroll
            for (int nt = 0; nt < 4; ++nt)
                bfr[nt] = *(const bf16x8*)&Bs[(nt * 16 + r) * LDT2
                                              + ks * 32 + quad * 8];

            #pragma unroll
            for (int mt = 0; mt < 2; ++mt)
                #pragma unroll
                for (int nt = 0; nt < 4; ++nt)
                    acc[mt][nt] = __builtin_amdgcn_mfma_f32_16x16x32_bf16(
                        af[mt], bfr[nt], acc[mt][nt], 0, 0, 0);
        }

        __syncthreads();
    }

    // epilogue: plain stores into this split's private partial tile
    float* Cp = Cpart + (size_t)blockIdx.y * (128 * Nc);
    #pragma unroll
    for (int mt = 0; mt < 2; ++mt) {
        int mrow = w * 32 + mt * 16 + quad * 4;
        #pragma unroll
        for (int nt = 0; nt < 4; ++nt) {
            int col = jt * 64 + nt * 16 + r;
            #pragma unroll
            for (int i = 0; i < 4; ++i)
                Cp[(size_t)(mrow + i) * Nc + col] = acc[mt][nt][i];
        }
    }
}

// ---------------------------------------------------------------------------
// Kernel 4: reduce fc1 partials + bias -> fc1_out (pre-relu, as before)
// ---------------------------------------------------------------------------
__global__ __launch_bounds__(256) void reduce_fc1_kernel(
    const float* __restrict__ part, const float* __restrict__ bias,
    float* __restrict__ outp)
{
    int i = blockIdx.x * 256 + threadIdx.x;       // float4 index
    float4 s = ((const float4*)part)[i];
    #pragma unroll
    for (int p = 1; p < KS1; ++p) {
        float4 v = ((const float4*)part)[(size_t)p * (NB * FC1_OUT / 4) + i];
        s.x += v.x; s.y += v.y; s.z += v.z; s.w += v.w;
    }
    float4 b = ((const float4*)bias)[i & (FC1_OUT / 4 - 1)];
    s.x += b.x; s.y += b.y; s.z += b.z; s.w += b.w;
    ((float4*)outp)[i] = s;
}

// ---------------------------------------------------------------------------
// Kernel 5: io layer — sums fc2 partials, +bias, relu, dot io_w, sigmoid
// ---------------------------------------------------------------------------
__global__ __launch_bounds__(256) void io_kernel(
    const float* __restrict__ part2, const float* __restrict__ fc2_b,
    const float* __restrict__ io_w, const float* __restrict__ io_b,
    float* __restrict__ out)
{
    int n = blockIdx.x;
    int tid = threadIdx.x;
    size_t base = (size_t)n * FC2_OUT + tid * 4;

    float4 v = ((const float4*)fc2_b)[tid];       // start from bias
    #pragma unroll
    for (int p = 0; p < KS2; ++p) {
        float4 t = *(const float4*)(part2 + (size_t)p * (NB * FC2_OUT) + base);
        v.x += t.x; v.y += t.y; v.z += t.z; v.w += t.w;
    }
    float4 wv = *(const float4*)(io_w + tid * 4);
    float s = fmaxf(v.x, 0.f) * wv.x + fmaxf(v.y, 0.f) * wv.y
            + fmaxf(v.z, 0.f) * wv.z + fmaxf(v.w, 0.f) * wv.w;
    #pragma unroll
    for (int off = 32; off > 0; off >>= 1)
        s += __shfl_down(s, off, 64);
    __shared__ float red[4];
    if ((tid & 63) == 0) red[tid >> 6] = s;
    __syncthreads();
    if (tid == 0) {
        float t = red[0] + red[1] + red[2] + red[3] + io_b[0];
        out[n] = 1.f / (1.f + expf(-t));
    }
}

// ---------------------------------------------------------------------------
// launch
// ---------------------------------------------------------------------------
extern "C" void kernel_launch(void* const* d_in, const int* in_sizes, int n_in,
                              void* d_out, int out_size, void* d_ws, size_t ws_size,
                              hipStream_t stream)
{
    const float* mask  = (const float*)d_in[0];
    const float* x     = (const float*)d_in[1];
    const float* w1    = (const float*)d_in[2];
    const float* b1    = (const float*)d_in[3];
    const float* w_off = (const float*)d_in[4];
    const float* w_dcn = (const float*)d_in[5];
    const float* b_dcn = (const float*)d_in[6];
    const float* w2    = (const float*)d_in[7];
    const float* b2    = (const float*)d_in[8];
    const float* fc1_w = (const float*)d_in[9];
    const float* fc1_b = (const float*)d_in[10];
    const float* fc2_w = (const float*)d_in[11];
    const float* fc2_b = (const float*)d_in[12];
    const float* io_w  = (const float*)d_in[13];
    const float* io_b  = (const float*)d_in[14];

    float* ws      = (float*)d_ws;
    float* h1      = ws + H1_OFF;
    float* pooled  = ws + POOL_OFF;
    float* fc1_out = ws + FC1_OFF;
    float* part1   = ws + H1_OFF;          // reuse h1 region (dead after DCN)
    float* part2   = ws + H1_OFF;          // reuse again (part1 dead after reduce)
    float* out     = (float*)d_out;

    // conv1: (N,9,128,128) -> h1 (N,2,128,128)
    conv1_kernel<<<dim3(16, NB), 256, 0, stream>>>(x, mask, w1, b1, h1);

    // fused offset-conv + DCN + 1x1 relu + 2x2 maxpool -> pooled (N,8192)
    fused_dcn_kernel<<<dim3(32, NB), 256, 0, stream>>>(
        h1, w_off, w_dcn, b_dcn, w2, b2, pooled);

    // fc1: (128,8192)@(8192,2048) bf16 MFMA, split-K 16 -> 512 blocks (2/CU)
    gemm_bf16_splitk<<<dim3(FC1_OUT / 64, KS1), 256, 0, stream>>>(
        pooled, fc1_w, part1, FC1_IN, FC1_OUT, FC1_IN / KS1, 0);

    // reduce fc1 partials + bias -> fc1_out
    reduce_fc1_kernel<<<NB * FC1_OUT / 4 / 256, 256, 0, stream>>>(
        part1, fc1_b, fc1_out);

    // fc2: relu(fc1) (128,2048)@(2048,1024) bf16 MFMA, split-K 32 -> 512 blocks
    gemm_bf16_splitk<<<dim3(FC2_OUT / 64, KS2), 256, 0, stream>>>(
        fc1_out, fc2_w, part2, FC1_OUT, FC2_OUT, FC1_OUT / KS2, 1);

    // io: sum fc2 partials + bias, relu, dot io_w, sigmoid -> out (128)
    io_kernel<<<NB, 256, 0, stream>>>(part2, fc2_b, io_w, io_b, out);
}